// Round 1
// baseline (421.196 us; speedup 1.0000x reference)
//
#include <hip/hip_runtime.h>
#include <cmath>

// DPI neuron forward: spike = (max(Imem + dImem, I0) - SPIKE_TH > 0).
// The einsum/Iampa_new path in the reference is dead code w.r.t. the returned
// `spike`, so this is a pure elementwise kernel over 7 state arrays [B, N_OUT].
// Memory-bound: 7 reads + 1 write of 64 MB each => ~537 MB HBM traffic.

namespace {
constexpr float F_I0    = 0.5e-13f;
constexpr float F_ITAU  = 4.25e-12f;   // ITAU_MEM
constexpr float F_IGAIN = 5.965e-11f;  // IGAIN_MEM
constexpr float F_ALPHA = 1.47e9f;
constexpr float F_DT    = 1e-3f;
constexpr float F_TH    = 0.00015f;    // SPIKE_TH
}

struct DpiC {
    float i0pow;    // I0 ** (1/(kappa+1))
    float kexp;     // kappa/(kappa+1)
    float tau_mem;  // C_MEM*UT/(kappa*ITAU_MEM)
};

__device__ __forceinline__ float dpi_spike(float im, float ah, float tr, float am,
                                           float nm, float sh, float gb, DpiC c) {
    float Ileak = F_ITAU + ah + gb;
    float Iin   = am + nm - sh;                    // IDC == 0
    Iin = (tr <= 0.0f) ? Iin : 0.0f;               // refractory mask
    Iin = fmaxf(Iin, F_I0);
    // Ifb = I0^(1/(k+1)) * Imem^(k/(k+1)) / (1 + exp(-ALPHA*(Imem - IGAIN)))
    float Ifb = c.i0pow * __powf(im, c.kexp) / (1.0f + __expf(-F_ALPHA * (im - F_IGAIN)));
    float f_imem   = Ifb / Ileak * (im + F_IGAIN);
    float Imem_inf = (F_IGAIN / F_ITAU) * (Iin - Ileak);
    float dImem = im / (c.tau_mem * (im + F_IGAIN))
                * (Imem_inf + f_imem - im * (1.0f + ah / F_ITAU)) * F_DT;
    float Imem_new = fmaxf(im + dImem, F_I0);
    // fast_sigmoid forward == Heaviside (strict >); margin is ~8 decades so
    // fast-math intrinsics cannot flip the binary result.
    return (Imem_new - F_TH > 0.0f) ? 1.0f : 0.0f;
}

__global__ void __launch_bounds__(256)
dpi_neuron_kernel(const float4* __restrict__ Imem,
                  const float4* __restrict__ Iahp,
                  const float4* __restrict__ timer_ref,
                  const float4* __restrict__ Iampa,
                  const float4* __restrict__ Inmda,
                  const float4* __restrict__ Ishunt,
                  const float4* __restrict__ Igaba,
                  float4* __restrict__ out,
                  int n4, int n_total, DpiC c) {
    int i = blockIdx.x * blockDim.x + threadIdx.x;
    if (i < n4) {
        float4 im = Imem[i], ah = Iahp[i], tr = timer_ref[i], am = Iampa[i];
        float4 nm = Inmda[i], sh = Ishunt[i], gb = Igaba[i];
        float4 o;
        o.x = dpi_spike(im.x, ah.x, tr.x, am.x, nm.x, sh.x, gb.x, c);
        o.y = dpi_spike(im.y, ah.y, tr.y, am.y, nm.y, sh.y, gb.y, c);
        o.z = dpi_spike(im.z, ah.z, tr.z, am.z, nm.z, sh.z, gb.z, c);
        o.w = dpi_spike(im.w, ah.w, tr.w, am.w, nm.w, sh.w, gb.w, c);
        out[i] = o;
    }
    // Scalar tail (n_total % 4), handled by one thread. n_total = 16.7M is
    // divisible by 4 so this is normally dead.
    if (i == 0) {
        const float* sIm = (const float*)Imem;  const float* sAh = (const float*)Iahp;
        const float* sTr = (const float*)timer_ref; const float* sAm = (const float*)Iampa;
        const float* sNm = (const float*)Inmda; const float* sSh = (const float*)Ishunt;
        const float* sGb = (const float*)Igaba; float* sOut = (float*)out;
        for (int j = n4 * 4; j < n_total; ++j)
            sOut[j] = dpi_spike(sIm[j], sAh[j], sTr[j], sAm[j], sNm[j], sSh[j], sGb[j], c);
    }
}

extern "C" void kernel_launch(void* const* d_in, const int* in_sizes, int n_in,
                              void* d_out, int out_size, void* d_ws, size_t ws_size,
                              hipStream_t stream) {
    // setup_inputs order:
    // 0: input [B,N_IN]   (unused -- feeds only dead-code Iampa_new)
    // 1: W_ampa [N_OUT,N_IN] (unused)
    // 2: Imem  3: Iahp  4: timer_ref  5: Iampa  6: Inmda  7: Ishunt  8: Igaba
    const float4* Imem   = (const float4*)d_in[2];
    const float4* Iahp   = (const float4*)d_in[3];
    const float4* tref   = (const float4*)d_in[4];
    const float4* Iampa  = (const float4*)d_in[5];
    const float4* Inmda  = (const float4*)d_in[6];
    const float4* Ishunt = (const float4*)d_in[7];
    const float4* Igaba  = (const float4*)d_in[8];
    float4* out = (float4*)d_out;

    const double KAPPA = (0.75 + 0.66) / 2.0;  // 0.705
    DpiC c;
    c.i0pow   = (float)std::pow(0.5e-13, 1.0 / (KAPPA + 1.0));
    c.kexp    = (float)(KAPPA / (KAPPA + 1.0));
    c.tau_mem = (float)(3e-12 * 25.0e-3 / (KAPPA * 4.25e-12));

    int n4 = out_size / 4;
    int blocks = (n4 + 255) / 256;
    hipLaunchKernelGGL(dpi_neuron_kernel, dim3(blocks), dim3(256), 0, stream,
                       Imem, Iahp, tref, Iampa, Inmda, Ishunt, Igaba, out,
                       n4, out_size, c);
}

// Round 3
// 412.339 us; speedup vs baseline: 1.0215x; 1.0215x over previous
//
#include <hip/hip_runtime.h>
#include <cmath>

// DPI neuron forward: spike = (max(Imem + dImem, I0) > SPIKE_TH).
// R1: VALU-issue-bound (65% VALUBusy, 23% HBM): 3 f32 division expansions +
// powf dominated (~123 VALU instrs/elem).
// R2/R3: all divisors are provably positive, so the strict inequality
//   dImem > TH - Imem
// becomes the division-free product comparison
//   im*(A*t + p*img) > (TH-im)*(tau/DT)*img*t
// with t = (1+exp(-ALPHA*(im-IGAIN)))*Ileak > 0,
//      p = I0^(1/(k+1)) * im^(k/(k+1))  (one v_log_f32 + fma + v_exp_f32),
//      A = (IGAIN/ITAU)*(Iin-Ileak) - im*(1 + ah/ITAU),  img = im + IGAIN.
// For all in-range inputs LHS < 0 < RHS with >9 decades margin, so the 1-ulp
// hardware log2/exp2 and the rearrangement cannot flip the binary output.

namespace {
constexpr float F_I0    = 0.5e-13f;
constexpr float F_ITAU  = 4.25e-12f;   // ITAU_MEM
constexpr float F_IGAIN = 5.965e-11f;  // IGAIN_MEM
constexpr float F_TH    = 0.00015f;    // SPIKE_TH
}

typedef float f32x4 __attribute__((ext_vector_type(4)));

struct DpiC {
    float kexp;            // k/(k+1)
    float l2_i0pow;        // log2(I0)/(k+1)
    float nalpha_l2e;      // -ALPHA * log2(e)
    float alpha_igain_l2e; //  ALPHA * IGAIN * log2(e)
    float gain_over_tau;   // IGAIN/ITAU
    float inv_itau;        // 1/ITAU
    float tau_over_dt;     // TAU_MEM/DT
};

__device__ __forceinline__ float dpi_spike(float im, float ah, float tr, float am,
                                           float nm, float sh, float gb, DpiC c) {
    float iin = (am + nm) - sh;
    iin = (tr <= 0.0f) ? iin : 0.0f;       // refractory mask (IDC == 0)
    iin = fmaxf(iin, F_I0);
    float ileak = (F_ITAU + ah) + gb;
    float img   = im + F_IGAIN;
    // p = exp2(kexp*log2(im) + l2_i0pow)   -- v_log_f32 computes log2
    float p = __builtin_amdgcn_exp2f(fmaf(c.kexp, __builtin_amdgcn_logf(im), c.l2_i0pow));
    // e = 1 + exp2(nalpha_l2e*im + alpha_igain_l2e)
    float e = 1.0f + __builtin_amdgcn_exp2f(fmaf(c.nalpha_l2e, im, c.alpha_igain_l2e));
    float t = e * ileak;                    // > 0
    float A = fmaf(c.gain_over_tau, iin - ileak, -im * fmaf(ah, c.inv_itau, 1.0f));
    float lhs = im * fmaf(A, t, p * img);
    float rhs = (F_TH - im) * (c.tau_over_dt * (img * t));
    return (lhs > rhs) ? 1.0f : 0.0f;
}

__global__ void __launch_bounds__(256)
dpi_neuron_kernel(const float4* __restrict__ Imem,
                  const float4* __restrict__ Iahp,
                  const float4* __restrict__ timer_ref,
                  const float4* __restrict__ Iampa,
                  const float4* __restrict__ Inmda,
                  const float4* __restrict__ Ishunt,
                  const float4* __restrict__ Igaba,
                  f32x4* __restrict__ out,
                  int n4, int n_total, DpiC c) {
    int i = blockIdx.x * blockDim.x + threadIdx.x;
    if (i < n4) {
        float4 im = Imem[i], ah = Iahp[i], tr = timer_ref[i], am = Iampa[i];
        float4 nm = Inmda[i], sh = Ishunt[i], gb = Igaba[i];
        f32x4 o;
        o.x = dpi_spike(im.x, ah.x, tr.x, am.x, nm.x, sh.x, gb.x, c);
        o.y = dpi_spike(im.y, ah.y, tr.y, am.y, nm.y, sh.y, gb.y, c);
        o.z = dpi_spike(im.z, ah.z, tr.z, am.z, nm.z, sh.z, gb.z, c);
        o.w = dpi_spike(im.w, ah.w, tr.w, am.w, nm.w, sh.w, gb.w, c);
        __builtin_nontemporal_store(o, &out[i]);  // streaming store
    }
    // Scalar tail (dead for n_total = 16.7M, kept for generality).
    if (i == 0) {
        const float* sIm = (const float*)Imem;  const float* sAh = (const float*)Iahp;
        const float* sTr = (const float*)timer_ref; const float* sAm = (const float*)Iampa;
        const float* sNm = (const float*)Inmda; const float* sSh = (const float*)Ishunt;
        const float* sGb = (const float*)Igaba; float* sOut = (float*)out;
        for (int j = n4 * 4; j < n_total; ++j)
            sOut[j] = dpi_spike(sIm[j], sAh[j], sTr[j], sAm[j], sNm[j], sSh[j], sGb[j], c);
    }
}

extern "C" void kernel_launch(void* const* d_in, const int* in_sizes, int n_in,
                              void* d_out, int out_size, void* d_ws, size_t ws_size,
                              hipStream_t stream) {
    // inputs: 0 input(unused), 1 W_ampa(unused), 2 Imem, 3 Iahp, 4 timer_ref,
    //         5 Iampa, 6 Inmda, 7 Ishunt, 8 Igaba
    const float4* Imem   = (const float4*)d_in[2];
    const float4* Iahp   = (const float4*)d_in[3];
    const float4* tref   = (const float4*)d_in[4];
    const float4* Iampa  = (const float4*)d_in[5];
    const float4* Inmda  = (const float4*)d_in[6];
    const float4* Ishunt = (const float4*)d_in[7];
    const float4* Igaba  = (const float4*)d_in[8];
    f32x4* out = (f32x4*)d_out;

    const double KAPPA = (0.75 + 0.66) / 2.0;    // 0.705
    const double I0 = 0.5e-13, ITAU = 4.25e-12, IGAIN = 5.965e-11;
    const double ALPHA = 1.47e9, DT = 1e-3;
    const double TAU_MEM = 3e-12 * 25.0e-3 / (KAPPA * ITAU);
    const double LOG2E = 1.4426950408889634;

    DpiC c;
    c.kexp            = (float)(KAPPA / (KAPPA + 1.0));
    c.l2_i0pow        = (float)(std::log2(I0) / (KAPPA + 1.0));
    c.nalpha_l2e      = (float)(-ALPHA * LOG2E);
    c.alpha_igain_l2e = (float)( ALPHA * IGAIN * LOG2E);
    c.gain_over_tau   = (float)(IGAIN / ITAU);
    c.inv_itau        = (float)(1.0 / ITAU);
    c.tau_over_dt     = (float)(TAU_MEM / DT);

    int n4 = out_size / 4;
    int blocks = (n4 + 255) / 256;
    hipLaunchKernelGGL(dpi_neuron_kernel, dim3(blocks), dim3(256), 0, stream,
                       Imem, Iahp, tref, Iampa, Inmda, Ishunt, Igaba, out,
                       n4, out_size, c);
}

// Round 4
// 389.260 us; speedup vs baseline: 1.0820x; 1.0593x over previous
//
#include <hip/hip_runtime.h>
#include <cmath>

// DPI neuron forward: spike = (max(Imem + dImem, I0) > SPIKE_TH).
// R1: VALU-bound (65% busy) -- 3 f32 div expansions + powf.
// R3: division-free product comparison -> VALUBusy 7%, dur 150us, but HBM only
//     2 TB/s (25%): neither pipe saturated. Logical traffic 512 MB @ 3.4 TB/s.
// R4: attack issue/latency structure: grid-stride (4 float4-chunks/thread)
//     so the compiler can software-pipeline loads across iterations with
//     partial vmcnt waits, + nontemporal loads/stores (data is streamed once;
//     don't allocate L3 on the missing half). If this is neutral, the limiter
//     is the harness's own 576 MB restore-copy drain contending for HBM.
//
// Math (from R2, unchanged): all divisors provably positive, so
//   dImem > TH - Imem  <=>  im*(A*t + p*img) > (TH-im)*(tau/DT)*img*t
// with t = (1+exp(-ALPHA*(im-IGAIN)))*Ileak > 0,
//      p = I0^(1/(k+1)) * im^(k/(k+1))  (v_log_f32 + fma + v_exp_f32),
//      A = (IGAIN/ITAU)*(Iin-Ileak) - im*(1 + ah/ITAU),  img = im + IGAIN.
// >9 decades of sign margin over the whole input range => 1-ulp hw log2/exp2
// and the rearrangement cannot flip the Heaviside output.

namespace {
constexpr float F_I0    = 0.5e-13f;
constexpr float F_ITAU  = 4.25e-12f;   // ITAU_MEM
constexpr float F_IGAIN = 5.965e-11f;  // IGAIN_MEM
constexpr float F_TH    = 0.00015f;    // SPIKE_TH
}

typedef float f32x4 __attribute__((ext_vector_type(4)));

struct DpiC {
    float kexp;            // k/(k+1)
    float l2_i0pow;        // log2(I0)/(k+1)
    float nalpha_l2e;      // -ALPHA * log2(e)
    float alpha_igain_l2e; //  ALPHA * IGAIN * log2(e)
    float gain_over_tau;   // IGAIN/ITAU
    float inv_itau;        // 1/ITAU
    float tau_over_dt;     // TAU_MEM/DT
};

__device__ __forceinline__ float dpi_spike(float im, float ah, float tr, float am,
                                           float nm, float sh, float gb, DpiC c) {
    float iin = (am + nm) - sh;
    iin = (tr <= 0.0f) ? iin : 0.0f;       // refractory mask (IDC == 0)
    iin = fmaxf(iin, F_I0);
    float ileak = (F_ITAU + ah) + gb;
    float img   = im + F_IGAIN;
    float p = __builtin_amdgcn_exp2f(fmaf(c.kexp, __builtin_amdgcn_logf(im), c.l2_i0pow));
    float e = 1.0f + __builtin_amdgcn_exp2f(fmaf(c.nalpha_l2e, im, c.alpha_igain_l2e));
    float t = e * ileak;                    // > 0
    float A = fmaf(c.gain_over_tau, iin - ileak, -im * fmaf(ah, c.inv_itau, 1.0f));
    float lhs = im * fmaf(A, t, p * img);
    float rhs = (F_TH - im) * (c.tau_over_dt * (img * t));
    return (lhs > rhs) ? 1.0f : 0.0f;
}

__global__ void __launch_bounds__(256)
dpi_neuron_kernel(const f32x4* __restrict__ Imem,
                  const f32x4* __restrict__ Iahp,
                  const f32x4* __restrict__ timer_ref,
                  const f32x4* __restrict__ Iampa,
                  const f32x4* __restrict__ Inmda,
                  const f32x4* __restrict__ Ishunt,
                  const f32x4* __restrict__ Igaba,
                  f32x4* __restrict__ out,
                  int n4, int n_total, DpiC c) {
    const int stride = gridDim.x * blockDim.x;
    const int i0 = blockIdx.x * blockDim.x + threadIdx.x;
    // Grid-stride: ~4 chunks/thread at the bench shape; compiler unrolls and
    // software-pipelines the loads with partial vmcnt waits.
    #pragma unroll 4
    for (int i = i0; i < n4; i += stride) {
        f32x4 im = __builtin_nontemporal_load(&Imem[i]);
        f32x4 ah = __builtin_nontemporal_load(&Iahp[i]);
        f32x4 tr = __builtin_nontemporal_load(&timer_ref[i]);
        f32x4 am = __builtin_nontemporal_load(&Iampa[i]);
        f32x4 nm = __builtin_nontemporal_load(&Inmda[i]);
        f32x4 sh = __builtin_nontemporal_load(&Ishunt[i]);
        f32x4 gb = __builtin_nontemporal_load(&Igaba[i]);
        f32x4 o;
        o.x = dpi_spike(im.x, ah.x, tr.x, am.x, nm.x, sh.x, gb.x, c);
        o.y = dpi_spike(im.y, ah.y, tr.y, am.y, nm.y, sh.y, gb.y, c);
        o.z = dpi_spike(im.z, ah.z, tr.z, am.z, nm.z, sh.z, gb.z, c);
        o.w = dpi_spike(im.w, ah.w, tr.w, am.w, nm.w, sh.w, gb.w, c);
        __builtin_nontemporal_store(o, &out[i]);
    }
    // Scalar tail (dead for n_total divisible by 4, kept for generality).
    if (i0 == 0) {
        const float* sIm = (const float*)Imem;  const float* sAh = (const float*)Iahp;
        const float* sTr = (const float*)timer_ref; const float* sAm = (const float*)Iampa;
        const float* sNm = (const float*)Inmda; const float* sSh = (const float*)Ishunt;
        const float* sGb = (const float*)Igaba; float* sOut = (float*)out;
        for (int j = n4 * 4; j < n_total; ++j)
            sOut[j] = dpi_spike(sIm[j], sAh[j], sTr[j], sAm[j], sNm[j], sSh[j], sGb[j], c);
    }
}

extern "C" void kernel_launch(void* const* d_in, const int* in_sizes, int n_in,
                              void* d_out, int out_size, void* d_ws, size_t ws_size,
                              hipStream_t stream) {
    // inputs: 0 input(unused), 1 W_ampa(unused), 2 Imem, 3 Iahp, 4 timer_ref,
    //         5 Iampa, 6 Inmda, 7 Ishunt, 8 Igaba
    const f32x4* Imem   = (const f32x4*)d_in[2];
    const f32x4* Iahp   = (const f32x4*)d_in[3];
    const f32x4* tref   = (const f32x4*)d_in[4];
    const f32x4* Iampa  = (const f32x4*)d_in[5];
    const f32x4* Inmda  = (const f32x4*)d_in[6];
    const f32x4* Ishunt = (const f32x4*)d_in[7];
    const f32x4* Igaba  = (const f32x4*)d_in[8];
    f32x4* out = (f32x4*)d_out;

    const double KAPPA = (0.75 + 0.66) / 2.0;    // 0.705
    const double I0 = 0.5e-13, ITAU = 4.25e-12, IGAIN = 5.965e-11;
    const double ALPHA = 1.47e9, DT = 1e-3;
    const double TAU_MEM = 3e-12 * 25.0e-3 / (KAPPA * ITAU);
    const double LOG2E = 1.4426950408889634;

    DpiC c;
    c.kexp            = (float)(KAPPA / (KAPPA + 1.0));
    c.l2_i0pow        = (float)(std::log2(I0) / (KAPPA + 1.0));
    c.nalpha_l2e      = (float)(-ALPHA * LOG2E);
    c.alpha_igain_l2e = (float)( ALPHA * IGAIN * LOG2E);
    c.gain_over_tau   = (float)(IGAIN / ITAU);
    c.inv_itau        = (float)(1.0 / ITAU);
    c.tau_over_dt     = (float)(TAU_MEM / DT);

    int n4 = out_size / 4;
    // ~4 grid-stride iterations per thread at n4 = 4.19M: 4096 blocks x 256.
    int blocks = (n4 + 4 * 256 - 1) / (4 * 256);
    if (blocks > 16384) blocks = 16384;
    if (blocks < 1) blocks = 1;
    hipLaunchKernelGGL(dpi_neuron_kernel, dim3(blocks), dim3(256), 0, stream,
                       Imem, Iahp, tref, Iampa, Inmda, Ishunt, Igaba, out,
                       n4, out_size, c);
}